// Round 1
// baseline (154.526 us; speedup 1.0000x reference)
//
#include <hip/hip_runtime.h>
#include <hip/hip_fp16.h>

#define B_ 256
#define D_ 1024
#define N_ 200000
#define K_ 64
#define SHIFT_ 24.0f
#define NCHUNK 3125   // N_/64 exactly
#define GRID2_ 512    // k2 grid size == chunk stride
#define NSLOT_ 8      // rk8 contention-splitting slots (indexed by g&7)

typedef short short8 __attribute__((ext_vector_type(8)));
typedef _Float16 f16x8 __attribute__((ext_vector_type(8)));
typedef float f32x4 __attribute__((ext_vector_type(4)));

__device__ __forceinline__ unsigned f2bf(float x) {
  unsigned u = __float_as_uint(x);
  return (u + 0x7fffu + ((u >> 16) & 1u)) >> 16;
}
__device__ __forceinline__ unsigned pack2(float a, float b) {
  return f2bf(a) | (f2bf(b) << 16);
}
__device__ __forceinline__ unsigned f2h(float x) {  // fp16 bits, RNE
  return (unsigned)__half_as_ushort(__float2half(x));
}
__device__ __forceinline__ f32x4 mfma16b(int4 a, int4 b, f32x4 c) {  // bf16
  return __builtin_amdgcn_mfma_f32_16x16x32_bf16(
      __builtin_bit_cast(short8, a), __builtin_bit_cast(short8, b), c, 0, 0, 0);
}
__device__ __forceinline__ f32x4 mfma16h(int4 a, int4 b, f32x4 c) {  // fp16
  return __builtin_amdgcn_mfma_f32_16x16x32_f16(
      __builtin_bit_cast(f16x8, a), __builtin_bit_cast(f16x8, b), c, 0, 0, 0);
}
__device__ __forceinline__ int p8hash(int k) { return ((k >> 3) ^ k) & 7; }

// ---------------------------------------------------------------------------
// K1: cue_outer[b][k] = sum_d cue[b][d] * w_cue[k][d]  (frozen compute)
//     + zeroes the fp32 atomic accumulators rk8/Z8 for K2 (stream-ordered).
// ---------------------------------------------------------------------------
__global__ __launch_bounds__(256) void k1_cueproj(
    const float* __restrict__ cue, const float* __restrict__ wcue,
    float* __restrict__ couter, float* __restrict__ rk8,
    float* __restrict__ Z8) {
  const int b    = blockIdx.x;
  const int tid  = threadIdx.x;
  const int w    = tid >> 6;
  const int lane = tid & 63;

  // zero this batch's accumulator slots (512 + 8 floats), retire early
  *(float2*)(rk8 + (size_t)b * (NSLOT_ * K_) + tid * 2) =
      make_float2(0.f, 0.f);
  if (tid < NSLOT_) Z8[b * NSLOT_ + tid] = 0.f;

  __shared__ float part[4][64][65];
  __shared__ float red[4][64];

  const float4 creg =
      *(const float4*)(cue + (size_t)b * D_ + w * 256 + lane * 4);
  const float* wbase = wcue + w * 256 + lane * 4;

#pragma unroll 8
  for (int k = 0; k < 64; ++k) {
    const float4 wv = *(const float4*)(wbase + (size_t)k * D_);
    part[w][k][lane] =
        creg.x * wv.x + creg.y * wv.y + creg.z * wv.z + creg.w * wv.w;
  }
  __syncthreads();

  const int k  = tid & 63;
  const int wq = tid >> 6;
  float a = 0.f;
#pragma unroll 8
  for (int j = 0; j < 64; ++j) a += part[wq][k][j];
  red[wq][k] = a;
  __syncthreads();
  if (tid < 64) {
    couter[b * K_ + tid] =
        red[0][tid] + red[1][tid] + red[2][tid] + red[3][tid];
  }
}

// ---------------------------------------------------------------------------
// K2: MFMA flash-attention. Main loop identical to the 132.8 µs version
// (38.4 KB LDS union, (256,2), VGPR ~128). Epilogue replaced: instead of
// staging S through LDS and streaming 16.8 MB of bf16 Spart partials to HBM,
// each wave atomicAdds its fp32 accumulators into rk8[b][g&7][k]
// (contention split 8 ways; ~64 blocks per line, memory-side fp32 atomics).
// Kills k3a and the Spart round-trip entirely; fp32 precision >= old bf16.
// ---------------------------------------------------------------------------
__global__ __launch_bounds__(256, 2) void k2_attend(
    const float* __restrict__ slot, const float* __restrict__ prio,
    const float* __restrict__ couter, float* __restrict__ rk8,
    float* __restrict__ Z8) {
  // union: sh_h[64*72] | sh_T[64*64] | sh_E[4][64*40] | sh_p[64]  = 38400 B
  __shared__ __align__(16) unsigned short sh_all[19200];
  unsigned short* const sh_h = sh_all;           // 4608 shorts
  unsigned short* const sh_T = sh_all + 4608;    // 4096 shorts
  unsigned short* const sh_E = sh_all + 8704;    // 10240 shorts (4 x 2560)
  float* const sh_p = (float*)(sh_all + 18944);  // 64 floats

  const int tid = threadIdx.x;
  const int g   = blockIdx.x;
  const int l   = tid & 63;
  const int w   = tid >> 6;
  const int c16 = l & 15;
  const int q   = l >> 4;

  // Q fragments (fp16), loaded once
  int4 qf[4][2];
#pragma unroll
  for (int bt = 0; bt < 4; ++bt) {
#pragma unroll
    for (int s = 0; s < 2; ++s) {
      const float* qp =
          couter + (size_t)(w * 64 + bt * 16 + c16) * K_ + s * 32 + q * 8;
      float4 va = *(const float4*)qp;
      float4 vb = *(const float4*)(qp + 4);
      qf[bt][s] = make_int4(
          (int)(f2h(va.x) | (f2h(va.y) << 16)),
          (int)(f2h(va.z) | (f2h(va.w) << 16)),
          (int)(f2h(vb.x) | (f2h(vb.y) << 16)),
          (int)(f2h(vb.z) | (f2h(vb.w) << 16)));
    }
  }

  f32x4 S[4][4];
#pragma unroll
  for (int a = 0; a < 4; ++a)
#pragma unroll
    for (int b = 0; b < 4; ++b) S[a][b] = (f32x4){0.f, 0.f, 0.f, 0.f};
  float zacc[4] = {0.f, 0.f, 0.f, 0.f};

  // prefetch chunk g
  float4 pf[4];
  float ppf = 0.f;
  {
    const float4* src = (const float4*)(slot + (size_t)g * 64 * K_);
#pragma unroll
    for (int i = 0; i < 4; ++i) pf[i] = src[tid + 256 * i];
    if (tid < 64) ppf = prio[g * 64 + tid];
  }

  for (int chunk = g; chunk < NCHUNK; chunk += GRID2_) {
    __syncthreads();
    // ---- stage: fp16 row-major (pad 72) for GEMM1 A; bf16 swizzled ^T ----
#pragma unroll
    for (int i = 0; i < 4; ++i) {
      const int f   = tid + 256 * i;
      const int row = f >> 4;
      const int c4  = (f & 15) * 4;
      float xs[4] = {pf[i].x, pf[i].y, pf[i].z, pf[i].w};
      unsigned hh[4];
#pragma unroll
      for (int j = 0; j < 4; ++j) {
        hh[j] = f2h(xs[j]);
        const int k = c4 + j;
        sh_T[k * 64 + (row ^ (p8hash(k) << 3))] =
            (unsigned short)f2bf(xs[j]);
      }
      *(uint2*)&sh_h[row * 72 + c4] =
          make_uint2(hh[0] | (hh[1] << 16), hh[2] | (hh[3] << 16));
    }
    if (tid < 64) sh_p[tid] = ppf;
    __syncthreads();

    // ---- prefetch next chunk (overlaps compute) ----
    const int nxt = chunk + GRID2_;
    if (nxt < NCHUNK) {
      const float4* src = (const float4*)(slot + (size_t)nxt * 64 * K_);
#pragma unroll
      for (int i = 0; i < 4; ++i) pf[i] = src[tid + 256 * i];
      if (tid < 64) ppf = prio[nxt * 64 + tid];
    }

    // ---- per n-half: GEMM1 (2 tiles) + E, then GEMM2 for that half ----
#pragma unroll
    for (int h = 0; h < 2; ++h) {
#pragma unroll
      for (int tt = 0; tt < 2; ++tt) {
        const int t = h * 2 + tt;
        f32x4 cc[4];
#pragma unroll
        for (int bt = 0; bt < 4; ++bt) cc[bt] = (f32x4){0.f, 0.f, 0.f, 0.f};
#pragma unroll
        for (int s = 0; s < 2; ++s) {
          const int off = (t * 16 + c16) * 72 + s * 32 + q * 8;
          int4 ah = *(const int4*)&sh_h[off];
#pragma unroll
          for (int bt = 0; bt < 4; ++bt)
            cc[bt] = mfma16h(ah, qf[bt][s], cc[bt]);
        }
        const float4 p = *(const float4*)&sh_p[t * 16 + q * 4];
#pragma unroll
        for (int bt = 0; bt < 4; ++bt) {
          float e0 = __expf(cc[bt][0] - SHIFT_) * p.x;
          float e1 = __expf(cc[bt][1] - SHIFT_) * p.y;
          float e2 = __expf(cc[bt][2] - SHIFT_) * p.z;
          float e3 = __expf(cc[bt][3] - SHIFT_) * p.w;
          zacc[bt] += (e0 + e1) + (e2 + e3);
          *(uint2*)&sh_E[w * 2560 + (bt * 16 + c16) * 40 + tt * 16 + q * 4] =
              make_uint2(pack2(e0, e1), pack2(e2, e3));
        }
      }
      // GEMM2 half h: S[b][kout] += sum_{n in half} E[b][n]*slot[n][kout]
      int4 bT[4];
#pragma unroll
      for (int ct = 0; ct < 4; ++ct) {
        const int k = ct * 16 + c16;
        bT[ct] = *(const int4*)&sh_T[k * 64 +
                                     ((h * 32 + q * 8) ^ (p8hash(k) << 3))];
      }
#pragma unroll
      for (int bt = 0; bt < 4; ++bt) {
        int4 aE =
            *(const int4*)&sh_E[w * 2560 + (bt * 16 + c16) * 40 + q * 8];
#pragma unroll
        for (int ct = 0; ct < 4; ++ct)
          S[bt][ct] = mfma16b(aE, bT[ct], S[bt][ct]);
      }
    }
  }

  // ---- epilogue: fp32 atomic accumulation into rk8[b][g&7][k] ----
  // S layout: batch = w*64 + bt*16 + q*4 + r, kout = ct*16 + c16
  const int slot8 = g & (NSLOT_ - 1);
#pragma unroll
  for (int bt = 0; bt < 4; ++bt) {
#pragma unroll
    for (int ct = 0; ct < 4; ++ct) {
#pragma unroll
      for (int r = 0; r < 4; ++r) {
        const int batch = w * 64 + bt * 16 + q * 4 + r;
        atomicAdd(rk8 + ((size_t)batch * NSLOT_ + slot8) * K_ + ct * 16 + c16,
                  S[bt][ct][r]);
      }
    }
  }
#pragma unroll
  for (int bt = 0; bt < 4; ++bt) {
    float z = zacc[bt];
    z += __shfl_xor(z, 16);
    z += __shfl_xor(z, 32);
    if (l < 16)
      atomicAdd(Z8 + (w * 64 + bt * 16 + c16) * NSLOT_ + slot8, z);
  }
}

// ---------------------------------------------------------------------------
// K3: rk = (sum_s rk8[b][s])/Z; decode via LDS-staged wdec tile.
// (was k3b; rkpart 8-way sum now reads the atomic accumulators directly,
//  Zpart 512-element scan + serial reduce replaced by an 8-float sum)
// ---------------------------------------------------------------------------
__global__ __launch_bounds__(256) void k3_decode(
    const float* __restrict__ rk8, const float* __restrict__ Z8,
    const float* __restrict__ wdec, float* __restrict__ out) {
  const int b   = blockIdx.x;
  const int j   = blockIdx.y;
  const int tid = threadIdx.x;

  __shared__ float rk[K_];
  __shared__ float wlds[256 * 65];

  float zz = 0.f;
#pragma unroll
  for (int s = 0; s < NSLOT_; ++s) zz += Z8[b * NSLOT_ + s];
  const float invZ = 1.0f / fmaxf(zz, 1e-30f);

  if (tid < K_) {
    float ssum = 0.f;
#pragma unroll
    for (int s = 0; s < NSLOT_; ++s)
      ssum += rk8[((size_t)b * NSLOT_ + s) * K_ + tid];
    rk[tid] = ssum;
  }

#pragma unroll
  for (int i = 0; i < 16; ++i) {
    const int f   = tid + 256 * i;
    const int row = f >> 4;
    const int c4  = (f & 15) * 4;
    const float4 v =
        *(const float4*)(wdec + (size_t)(j * 256 + row) * K_ + c4);
    wlds[row * 65 + c4 + 0] = v.x;
    wlds[row * 65 + c4 + 1] = v.y;
    wlds[row * 65 + c4 + 2] = v.z;
    wlds[row * 65 + c4 + 3] = v.w;
  }
  __syncthreads();

  float acc = 0.f;
#pragma unroll
  for (int kk = 0; kk < 64; ++kk) acc += rk[kk] * wlds[tid * 65 + kk];
  out[(size_t)b * D_ + j * 256 + tid] = acc * invZ;
}

// ---------------------------------------------------------------------------
extern "C" void kernel_launch(void* const* d_in, const int* in_sizes, int n_in,
                              void* d_out, int out_size, void* d_ws,
                              size_t ws_size, hipStream_t stream) {
  const float* cue  = (const float*)d_in[0];
  const float* slot = (const float*)d_in[1];
  const float* prio = (const float*)d_in[2];
  const float* wcue = (const float*)d_in[3];
  const float* wdec = (const float*)d_in[4];
  float* out = (float*)d_out;

  // ws: couter fp32 [B][K] (64KB) | rk8 fp32 [B][8][K] (512KB) |
  //     Z8 fp32 [B][8] (8KB)     — Spart/Zpart/rkpart eliminated.
  float* couter = (float*)d_ws;
  float* rk8    = couter + (size_t)B_ * K_;
  float* Z8     = rk8 + (size_t)B_ * NSLOT_ * K_;

  k1_cueproj<<<dim3(B_), dim3(256), 0, stream>>>(cue, wcue, couter, rk8, Z8);
  k2_attend<<<dim3(GRID2_), dim3(256), 0, stream>>>(slot, prio, couter, rk8,
                                                    Z8);
  k3_decode<<<dim3(B_, 4), dim3(256), 0, stream>>>(rk8, Z8, wdec, out);
}

// Round 2
// 135.682 us; speedup vs baseline: 1.1389x; 1.1389x over previous
//
#include <hip/hip_runtime.h>
#include <hip/hip_fp16.h>

#define B_ 256
#define D_ 1024
#define N_ 200000
#define K_ 64
#define SHIFT_ 24.0f
#define NCHUNK 3125   // N_/64 exactly
#define SL_ 8         // K3a G-slices

typedef short short8 __attribute__((ext_vector_type(8)));
typedef _Float16 f16x8 __attribute__((ext_vector_type(8)));
typedef float f32x4 __attribute__((ext_vector_type(4)));

__device__ __forceinline__ unsigned f2bf(float x) {
  unsigned u = __float_as_uint(x);
  return (u + 0x7fffu + ((u >> 16) & 1u)) >> 16;
}
__device__ __forceinline__ unsigned pack2(float a, float b) {
  return f2bf(a) | (f2bf(b) << 16);
}
__device__ __forceinline__ float bf2f(unsigned short u) {
  return __uint_as_float(((unsigned)u) << 16);
}
__device__ __forceinline__ unsigned f2h(float x) {  // fp16 bits, RNE
  return (unsigned)__half_as_ushort(__float2half(x));
}
__device__ __forceinline__ f32x4 mfma16b(int4 a, int4 b, f32x4 c) {  // bf16
  return __builtin_amdgcn_mfma_f32_16x16x32_bf16(
      __builtin_bit_cast(short8, a), __builtin_bit_cast(short8, b), c, 0, 0, 0);
}
__device__ __forceinline__ f32x4 mfma16h(int4 a, int4 b, f32x4 c) {  // fp16
  return __builtin_amdgcn_mfma_f32_16x16x32_f16(
      __builtin_bit_cast(f16x8, a), __builtin_bit_cast(f16x8, b), c, 0, 0, 0);
}
__device__ __forceinline__ int p8hash(int k) { return ((k >> 3) ^ k) & 7; }

// ---------------------------------------------------------------------------
// K1: cue_outer[b][k] = sum_d cue[b][d] * w_cue[k][d]  (frozen)
// ---------------------------------------------------------------------------
__global__ __launch_bounds__(256) void k1_cueproj(
    const float* __restrict__ cue, const float* __restrict__ wcue,
    float* __restrict__ couter) {
  const int b    = blockIdx.x;
  const int tid  = threadIdx.x;
  const int w    = tid >> 6;
  const int lane = tid & 63;

  __shared__ float part[4][64][65];
  __shared__ float red[4][64];

  const float4 creg =
      *(const float4*)(cue + (size_t)b * D_ + w * 256 + lane * 4);
  const float* wbase = wcue + w * 256 + lane * 4;

#pragma unroll 8
  for (int k = 0; k < 64; ++k) {
    const float4 wv = *(const float4*)(wbase + (size_t)k * D_);
    part[w][k][lane] =
        creg.x * wv.x + creg.y * wv.y + creg.z * wv.z + creg.w * wv.w;
  }
  __syncthreads();

  const int k  = tid & 63;
  const int wq = tid >> 6;
  float a = 0.f;
#pragma unroll 8
  for (int j = 0; j < 64; ++j) a += part[wq][k][j];
  red[wq][k] = a;
  __syncthreads();
  if (tid < 64) {
    couter[b * K_ + tid] =
        red[0][tid] + red[1][tid] + red[2][tid] + red[3][tid];
  }
}

// ---------------------------------------------------------------------------
// K2: MFMA flash-attention. Epilogue: Spart bf16 partials (round-0 proven
// scheme — atomics were 0.38 op/ns due to cross-XCD line ping-pong).
// NEW: ping-pong slot staging (sh_h/sh_T/sh_p x2). One barrier per chunk:
// body = { stage chunk c+1 into buf p^1  ||  compute chunk c from buf p }
// with compile-time buffer parity so LDS offsets are constants (alias-free,
// compiler can interleave staging ds_writes with MFMA). LDS 54.5 KB,
// 2 blocks/CU (unchanged: grid 512 = 2 blocks/CU anyway).
// ---------------------------------------------------------------------------
__global__ __launch_bounds__(256, 2) void k2_attend(
    const float* __restrict__ slot, const float* __restrict__ prio,
    const float* __restrict__ couter, unsigned short* __restrict__ Spart,
    float* __restrict__ Zpart, int G) {
  // sh_h[2][4608] | sh_T[2][4096] | sh_E[5120] | sh_p[2][64]f = 55808 B
  // epilogue overlay view: [4][64][72] shorts = 36864 B (fits)
  __shared__ __align__(16) unsigned short sh_all[27904];
  unsigned short* const sh_h = sh_all;            // 2 x 4608 shorts
  unsigned short* const sh_T = sh_all + 9216;     // 2 x 4096 shorts
  unsigned short* const sh_E = sh_all + 17408;    // 10240 shorts (4 x 2560)
  float* const sh_p = (float*)(sh_all + 27648);   // 2 x 64 floats

  const int tid = threadIdx.x;
  const int g   = blockIdx.x;
  const int l   = tid & 63;
  const int w   = tid >> 6;
  const int c16 = l & 15;
  const int q   = l >> 4;

  // Q fragments (fp16), loaded once
  int4 qf[4][2];
#pragma unroll
  for (int bt = 0; bt < 4; ++bt) {
#pragma unroll
    for (int s = 0; s < 2; ++s) {
      const float* qp =
          couter + (size_t)(w * 64 + bt * 16 + c16) * K_ + s * 32 + q * 8;
      float4 va = *(const float4*)qp;
      float4 vb = *(const float4*)(qp + 4);
      qf[bt][s] = make_int4(
          (int)(f2h(va.x) | (f2h(va.y) << 16)),
          (int)(f2h(va.z) | (f2h(va.w) << 16)),
          (int)(f2h(vb.x) | (f2h(vb.y) << 16)),
          (int)(f2h(vb.z) | (f2h(vb.w) << 16)));
    }
  }

  f32x4 S[4][4];
#pragma unroll
  for (int a = 0; a < 4; ++a)
#pragma unroll
    for (int b = 0; b < 4; ++b) S[a][b] = (f32x4){0.f, 0.f, 0.f, 0.f};
  float zacc[4] = {0.f, 0.f, 0.f, 0.f};

  float4 pf[4];
  float ppf = 0.f;

  auto prefetch = [&](const int c) {
    const float4* src = (const float4*)(slot + (size_t)c * 64 * K_);
#pragma unroll
    for (int i = 0; i < 4; ++i) pf[i] = src[tid + 256 * i];
    if (tid < 64) ppf = prio[c * 64 + tid];
  };

  // stage pf/ppf into buffer PP (call with literal 0/1 -> const LDS offsets)
  auto stageN = [&](const int PP) {
    unsigned short* const hB = sh_h + PP * 4608;
    unsigned short* const TB = sh_T + PP * 4096;
#pragma unroll
    for (int i = 0; i < 4; ++i) {
      const int f   = tid + 256 * i;
      const int row = f >> 4;
      const int c4  = (f & 15) * 4;
      float xs[4] = {pf[i].x, pf[i].y, pf[i].z, pf[i].w};
      unsigned hh[4];
#pragma unroll
      for (int j = 0; j < 4; ++j) {
        hh[j] = f2h(xs[j]);
        const int kk = c4 + j;
        TB[kk * 64 + (row ^ (p8hash(kk) << 3))] =
            (unsigned short)f2bf(xs[j]);
      }
      *(uint2*)&hB[row * 72 + c4] =
          make_uint2(hh[0] | (hh[1] << 16), hh[2] | (hh[3] << 16));
    }
    if (tid < 64) sh_p[PP * 64 + tid] = ppf;
  };

  auto computeC = [&](const int PP) {
    const unsigned short* const hB = sh_h + PP * 4608;
    const unsigned short* const TB = sh_T + PP * 4096;
    const float* const pB = sh_p + PP * 64;
#pragma unroll
    for (int h = 0; h < 2; ++h) {
#pragma unroll
      for (int tt = 0; tt < 2; ++tt) {
        const int t = h * 2 + tt;
        f32x4 cc[4];
#pragma unroll
        for (int bt = 0; bt < 4; ++bt) cc[bt] = (f32x4){0.f, 0.f, 0.f, 0.f};
#pragma unroll
        for (int s = 0; s < 2; ++s) {
          const int off = (t * 16 + c16) * 72 + s * 32 + q * 8;
          int4 ah = *(const int4*)&hB[off];
#pragma unroll
          for (int bt = 0; bt < 4; ++bt)
            cc[bt] = mfma16h(ah, qf[bt][s], cc[bt]);
        }
        const float4 p = *(const float4*)&pB[t * 16 + q * 4];
#pragma unroll
        for (int bt = 0; bt < 4; ++bt) {
          float e0 = __expf(cc[bt][0] - SHIFT_) * p.x;
          float e1 = __expf(cc[bt][1] - SHIFT_) * p.y;
          float e2 = __expf(cc[bt][2] - SHIFT_) * p.z;
          float e3 = __expf(cc[bt][3] - SHIFT_) * p.w;
          zacc[bt] += (e0 + e1) + (e2 + e3);
          *(uint2*)&sh_E[w * 2560 + (bt * 16 + c16) * 40 + tt * 16 + q * 4] =
              make_uint2(pack2(e0, e1), pack2(e2, e3));
        }
      }
      // GEMM2 half h: S[b][kout] += sum_{n in half} E[b][n]*slot[n][kout]
      int4 bT[4];
#pragma unroll
      for (int ct = 0; ct < 4; ++ct) {
        const int k = ct * 16 + c16;
        bT[ct] = *(const int4*)&TB[k * 64 +
                                   ((h * 32 + q * 8) ^ (p8hash(k) << 3))];
      }
#pragma unroll
      for (int bt = 0; bt < 4; ++bt) {
        int4 aE =
            *(const int4*)&sh_E[w * 2560 + (bt * 16 + c16) * 40 + q * 8];
#pragma unroll
        for (int ct = 0; ct < 4; ++ct)
          S[bt][ct] = mfma16b(aE, bT[ct], S[bt][ct]);
      }
    }
  };

  // ---- prologue: load + stage chunk g into buf0, prefetch g+G ----
  prefetch(g);
  stageN(0);
  if (g + G < NCHUNK) prefetch(g + G);
  __syncthreads();

  // ---- main loop: 1 barrier per chunk, 2x unrolled for const parity ----
  int chunk = g;
  while (true) {
    {  // buffer 0 holds 'chunk'
      const int nxt = chunk + G;
      if (nxt < NCHUNK) {
        stageN(1);
        if (nxt + G < NCHUNK) prefetch(nxt + G);
      }
      computeC(0);
      __syncthreads();
      chunk = nxt;
      if (chunk >= NCHUNK) break;
    }
    {  // buffer 1 holds 'chunk'
      const int nxt = chunk + G;
      if (nxt < NCHUNK) {
        stageN(0);
        if (nxt + G < NCHUNK) prefetch(nxt + G);
      }
      computeC(1);
      __syncthreads();
      chunk = nxt;
      if (chunk >= NCHUNK) break;
    }
  }

  // ---- epilogue: stage S (bf16) into overlay [4][64][72], then stream ----
  __syncthreads();  // all chunk compute done; sh_all reusable
  unsigned short* const stg = sh_all;
#pragma unroll
  for (int bt = 0; bt < 4; ++bt) {
#pragma unroll
    for (int ct = 0; ct < 4; ++ct) {
#pragma unroll
      for (int r = 0; r < 4; ++r) {
        stg[(w * 64 + bt * 16 + q * 4 + r) * 72 + ct * 16 + c16] =
            (unsigned short)f2bf(S[bt][ct][r]);
      }
    }
  }
  __syncthreads();
#pragma unroll
  for (int i = 0; i < 8; ++i) {
    const int idx   = tid + 256 * i;
    const int batch = idx >> 3;
    const int seg   = idx & 7;
    uint4 v = *(const uint4*)&stg[batch * 72 + seg * 8];
    *(uint4*)&Spart[((size_t)batch * G + g) * K_ + seg * 8] = v;
  }
#pragma unroll
  for (int bt = 0; bt < 4; ++bt) {
    float z = zacc[bt];
    z += __shfl_xor(z, 16);
    z += __shfl_xor(z, 32);
    if (l < 16) Zpart[(size_t)(w * 64 + bt * 16 + c16) * G + g] = z;
  }
}

// ---------------------------------------------------------------------------
// K3a: block (b,s) reduces Spart g-slice -> rkpart[b][s][k]. (frozen)
// ---------------------------------------------------------------------------
__global__ __launch_bounds__(256) void k3a_reduce(
    const unsigned short* __restrict__ Spart, float* __restrict__ rkpart,
    int G) {
  const int b   = blockIdx.x;
  const int s   = blockIdx.y;
  const int tid = threadIdx.x;
  const int gq  = tid >> 3;
  const int k8  = tid & 7;

  __shared__ float part[32][65];

  const int gcnt = G / SL_;
  const int gbeg = s * gcnt;

  float acc[8] = {0.f, 0.f, 0.f, 0.f, 0.f, 0.f, 0.f, 0.f};
  const unsigned short* sp = Spart + (size_t)b * G * K_ + k8 * 8;
  for (int gg = gq; gg < gcnt; gg += 32) {
    uint4 v = *(const uint4*)(sp + (size_t)(gbeg + gg) * K_);
    acc[0] += __uint_as_float(v.x << 16);
    acc[1] += __uint_as_float(v.x & 0xffff0000u);
    acc[2] += __uint_as_float(v.y << 16);
    acc[3] += __uint_as_float(v.y & 0xffff0000u);
    acc[4] += __uint_as_float(v.z << 16);
    acc[5] += __uint_as_float(v.z & 0xffff0000u);
    acc[6] += __uint_as_float(v.w << 16);
    acc[7] += __uint_as_float(v.w & 0xffff0000u);
  }
#pragma unroll
  for (int j = 0; j < 8; ++j) part[gq][k8 * 8 + j] = acc[j];
  __syncthreads();

  if (tid < 64) {
    float sum = 0.f;
#pragma unroll
    for (int r = 0; r < 32; ++r) sum += part[r][tid];
    rkpart[((size_t)b * SL_ + s) * K_ + tid] = sum;
  }
}

// ---------------------------------------------------------------------------
// K3b: rk = (sum_s rkpart)/Z; decode via LDS-staged wdec tile. (frozen)
// ---------------------------------------------------------------------------
__global__ __launch_bounds__(256) void k3b_decode(
    const float* __restrict__ rkpart, const float* __restrict__ Zpart,
    const float* __restrict__ wdec, float* __restrict__ out, int G) {
  const int b   = blockIdx.x;
  const int j   = blockIdx.y;
  const int tid = threadIdx.x;

  __shared__ float zred[256];
  __shared__ float rk[K_];
  __shared__ float wlds[256 * 65];

  float zp = 0.f;
  const float* zpp = Zpart + (size_t)b * G;
  for (int g = tid; g < G; g += 256) zp += zpp[g];
  zred[tid] = zp;
  __syncthreads();

  if (tid < K_) {
    float ssum = 0.f;
#pragma unroll
    for (int s = 0; s < SL_; ++s)
      ssum += rkpart[((size_t)b * SL_ + s) * K_ + tid];
    if (tid == 0) {
      float zz = 0.f;
      for (int i = 0; i < 256; ++i) zz += zred[i];
      zred[0] = fmaxf(zz, 1e-30f);
    }
    rk[tid] = ssum;
  }
  __syncthreads();
  const float invZ = 1.0f / zred[0];

#pragma unroll
  for (int i = 0; i < 16; ++i) {
    const int f   = tid + 256 * i;
    const int row = f >> 4;
    const int c4  = (f & 15) * 4;
    const float4 v =
        *(const float4*)(wdec + (size_t)(j * 256 + row) * K_ + c4);
    wlds[row * 65 + c4 + 0] = v.x;
    wlds[row * 65 + c4 + 1] = v.y;
    wlds[row * 65 + c4 + 2] = v.z;
    wlds[row * 65 + c4 + 3] = v.w;
  }
  __syncthreads();

  float acc = 0.f;
#pragma unroll
  for (int kk = 0; kk < 64; ++kk) acc += rk[kk] * wlds[tid * 65 + kk];
  out[(size_t)b * D_ + j * 256 + tid] = acc * invZ;
}

// ---------------------------------------------------------------------------
extern "C" void kernel_launch(void* const* d_in, const int* in_sizes, int n_in,
                              void* d_out, int out_size, void* d_ws,
                              size_t ws_size, hipStream_t stream) {
  const float* cue  = (const float*)d_in[0];
  const float* slot = (const float*)d_in[1];
  const float* prio = (const float*)d_in[2];
  const float* wcue = (const float*)d_in[3];
  const float* wdec = (const float*)d_in[4];
  float* out = (float*)d_out;

  // ws: couter (64KB) | Spart bf16 [B][G][64] | Zpart fp32 [B][G] |
  //     rkpart fp32 [B][8][64] (512KB)
  const size_t per_g = (size_t)B_ * K_ * 2 + (size_t)B_ * 4;  // 33792 B
  long long avail = (long long)ws_size - 65536 - 524288;
  int G = (int)(avail > 0 ? avail / (long long)per_g : SL_);
  if (G > 512) G = 512;     // 6.1 chunks/block, 16.8MB Spart
  G &= ~(SL_ - 1);          // K3a needs G % 8 == 0
  if (G < SL_) G = SL_;

  float* couter         = (float*)d_ws;
  unsigned short* Spart = (unsigned short*)(couter + 16384);
  float* Zpart          = (float*)(Spart + (size_t)B_ * G * K_);
  float* rkpart         = Zpart + (size_t)B_ * G;

  k1_cueproj<<<dim3(B_), dim3(256), 0, stream>>>(cue, wcue, couter);
  k2_attend<<<dim3(G), dim3(256), 0, stream>>>(slot, prio, couter, Spart,
                                               Zpart, G);
  k3a_reduce<<<dim3(B_, SL_), dim3(256), 0, stream>>>(Spart, rkpart, G);
  k3b_decode<<<dim3(B_, 4), dim3(256), 0, stream>>>(rkpart, Zpart, wdec, out,
                                                    G);
}